// Round 1
// baseline (287.470 us; speedup 1.0000x reference)
//
#include <hip/hip_runtime.h>
#include <stdint.h>

// Problem: B=8, N=4096, C=512, H=8, D=64. fp32 in/out, bf16 MFMA internally.
#define NB 8
#define NN 4096
#define NC 512
#define NH 8
#define ATTN_CH 16   // token chunks for k_attn

typedef __bf16 bf16x8 __attribute__((ext_vector_type(8)));
typedef float floatx4 __attribute__((ext_vector_type(4)));

__device__ __forceinline__ unsigned short f2bf(float f) {
  union { float f; unsigned u; } v; v.f = f;
  return (unsigned short)((v.u + 0x7fffu + ((v.u >> 16) & 1u)) >> 16);
}
__device__ __forceinline__ float2 bfp2f(unsigned u) {
  union { unsigned x; float f; } lo, hi;
  lo.x = u << 16; hi.x = u & 0xffff0000u;
  return make_float2(lo.f, hi.f);
}

// async 16B global->LDS (DMA). LDS dest = wave-uniform base + lane*16.
__device__ __forceinline__ void async_ld16(void* lds, const void* g) {
  auto* gp = (const __attribute__((address_space(1))) unsigned int*)(uintptr_t)g;
  auto* lp = (__attribute__((address_space(3))) unsigned int*)(uintptr_t)lds;
  __builtin_amdgcn_global_load_lds(gp, lp, 16, 0, 0);
}

// ---------- 1) fused: x fp32->bf16 convert  +  w_qkv transpose->bf16 ----------
__global__ __launch_bounds__(256) void k_prep(const float* __restrict__ x,
                                              unsigned short* __restrict__ xb,
                                              const float* __restrict__ w,
                                              unsigned short* __restrict__ wt) {
  int bid = blockIdx.x;
  if (bid < 16384) {
    int i = (bid * 256 + threadIdx.x) * 4;
    float4 v = *(const float4*)(x + i);
    ushort4 o;
    o.x = f2bf(v.x); o.y = f2bf(v.y); o.z = f2bf(v.z); o.w = f2bf(v.w);
    *(ushort4*)(xb + i) = o;
    return;
  }
  // transpose 64x64 tile of w [512][1536] -> wt [1536][512]
  __shared__ float tile[64][65];
  int b2 = bid - 16384;                  // 0..191
  int nn0 = (b2 % 24) * 64, kk0 = (b2 / 24) * 64;
  int t = threadIdx.x;
#pragma unroll
  for (int i = 0; i < 16; i++) {
    int id = t + i * 256;
    int r = id >> 6, c = id & 63;
    tile[c][r] = w[(size_t)(kk0 + r) * 1536 + nn0 + c];
  }
  __syncthreads();
#pragma unroll
  for (int i = 0; i < 16; i++) {
    int id = t + i * 256;
    int rn = id >> 6, ck = id & 63;
    wt[(size_t)(nn0 + rn) * 512 + kk0 + ck] = f2bf(tile[rn][ck]);
  }
}

// ---------- 2) qkv GEMM: [32768x512] @ [512x1536] + bias -> bf16 ----------
// 256x256 tile, 8 waves, double-buffered K-tiles, counted vmcnt (T3+T4),
// setprio around MFMA clusters (T5), XOR 16B-slot swizzle both sides (T2).
__global__ __launch_bounds__(512, 2) void k_gemm_qkv(const unsigned short* __restrict__ A,   // [32768][512]
                                                     const unsigned short* __restrict__ Bt,  // [1536][512]
                                                     const float* __restrict__ bias,         // [1536]
                                                     unsigned short* __restrict__ Cq) {      // [32768][1536]
  const int LDA = 512, LDB = 512, LDC = 1536;
  int bid = blockIdx.x;                  // 768 blocks: 128 m-tiles x 6 n-tiles
  int xcd = bid & 7, local = bid >> 3;   // local 0..95
  int mloc = local / 6, nt = local - mloc * 6;
  int m0 = (xcd * 16 + mloc) * 256, n0 = nt * 256;

  int tid = threadIdx.x;
  int lane = tid & 63, w = tid >> 6;     // 8 waves
  int wrb = (w >> 2) * 128;              // wave row base within tile
  int wcb = (w & 3) * 64;                // wave col base within tile
  int quad = lane >> 4, rr = lane & 15;
  int r8 = lane >> 3, cg = lane & 7;
  int cgs8 = (cg ^ r8) * 8;
  const int swz = rr & 7;
  int w8 = w * 8;

  __shared__ __align__(16) unsigned short As[2][256 * 64];
  __shared__ __align__(16) unsigned short Bs[2][256 * 64];

  floatx4 acc[8][4];
#pragma unroll
  for (int i = 0; i < 8; i++)
#pragma unroll
    for (int j = 0; j < 4; j++) acc[i][j] = (floatx4){0.f, 0.f, 0.f, 0.f};

  // stage one full K-tile (A 256x64 + B 256x64) : 8 global_load_lds per thread
  auto stage = [&](int ss, int kt) {
    int k0 = kt << 6;
#pragma unroll
    for (int i = 0; i < 4; i++) {
      int rb = i * 64 + w8;              // 8-row chunk per wave-instr
      async_ld16(&As[ss][rb * 64], A + (size_t)(m0 + rb + r8) * LDA + k0 + cgs8);
      async_ld16(&Bs[ss][rb * 64], Bt + (size_t)(n0 + rb + r8) * LDB + k0 + cgs8);
    }
  };

  auto compute = [&](int ss) {
#pragma unroll
    for (int kk = 0; kk < 2; kk++) {
      int ksl = (((kk << 2) + quad) ^ swz) << 3;
      bf16x8 af[8];
#pragma unroll
      for (int mi = 0; mi < 8; mi++)
        af[mi] = *(const bf16x8*)&As[ss][(wrb + mi * 16 + rr) * 64 + ksl];
      bf16x8 bf[2];
#pragma unroll
      for (int ni = 0; ni < 2; ni++)
        bf[ni] = *(const bf16x8*)&Bs[ss][(wcb + ni * 16 + rr) * 64 + ksl];
      __builtin_amdgcn_s_setprio(1);
#pragma unroll
      for (int mi = 0; mi < 8; mi++)
#pragma unroll
        for (int ni = 0; ni < 2; ni++)
          acc[mi][ni] = __builtin_amdgcn_mfma_f32_16x16x32_bf16(af[mi], bf[ni], acc[mi][ni], 0, 0, 0);
      __builtin_amdgcn_s_setprio(0);
#pragma unroll
      for (int ni = 0; ni < 2; ni++)
        bf[ni] = *(const bf16x8*)&Bs[ss][(wcb + (ni + 2) * 16 + rr) * 64 + ksl];
      __builtin_amdgcn_s_setprio(1);
#pragma unroll
      for (int mi = 0; mi < 8; mi++)
#pragma unroll
        for (int ni = 0; ni < 2; ni++)
          acc[mi][ni + 2] = __builtin_amdgcn_mfma_f32_16x16x32_bf16(af[mi], bf[ni], acc[mi][ni + 2], 0, 0, 0);
      __builtin_amdgcn_s_setprio(0);
    }
  };

  stage(0, 0);
  stage(1, 1);
#pragma unroll 1
  for (int t = 0; t < 8; t++) {
    // tile t's 8 loads are the oldest; tile t+1's 8 may stay in flight.
    if (t < 7) asm volatile("s_waitcnt vmcnt(8)" ::: "memory");
    else       asm volatile("s_waitcnt vmcnt(0)" ::: "memory");
    __builtin_amdgcn_s_barrier();
    __builtin_amdgcn_sched_barrier(0);
    compute(t & 1);
    __builtin_amdgcn_sched_barrier(0);
    __builtin_amdgcn_s_barrier();      // all waves done reading side t&1
    if (t < 6) stage(t & 1, t + 2);    // overlaps compute of tile t+1
  }

#pragma unroll
  for (int ni = 0; ni < 4; ni++) {
    int col = n0 + wcb + ni * 16 + rr;
    float bv = bias[col];
#pragma unroll
    for (int mi = 0; mi < 8; mi++) {
      int rbase = m0 + wrb + mi * 16 + quad * 4;
#pragma unroll
      for (int r = 0; r < 4; r++)
        Cq[(size_t)(rbase + r) * LDC + col] = f2bf(acc[mi][ni][r] + bv);
    }
  }
}

// ---------- 3) attn logits via MFMA, fused L2-norm. grid (chunk16, h8, b8) ----------
__global__ __launch_bounds__(256) void k_attn(const unsigned short* __restrict__ QKV,
                                              float* __restrict__ logits_p) {
  int chunk = blockIdx.x, hh = blockIdx.y, b = blockIdx.z;
  int tid = threadIdx.x, w = tid >> 6, l = tid & 63;
  int quad = l >> 4, rr = l & 15;

  __shared__ __align__(16) unsigned char smem[40960];
  unsigned short* qT = (unsigned short*)smem + w * 5120;   // 64*40 halfwords
  unsigned short* kT = qT + 2560;
  float* ps = (float*)smem;                                 // 16KB, reused after barrier

  floatx4 acc[4][4];
#pragma unroll
  for (int i = 0; i < 4; i++)
#pragma unroll
    for (int j = 0; j < 4; j++) acc[i][j] = (floatx4){0.f, 0.f, 0.f, 0.f};

  int tok8 = l >> 3;
  int seg = l & 7;
  int sw = seg & 3;

  for (int s = 0; s < 2; s++) {
    int nbase = chunk * 256 + w * 64 + s * 32;
#pragma unroll
    for (int c = 0; c < 4; c++) {
      int n = nbase + c * 8 + tok8;
      const unsigned short* p = QKV + (size_t)(b * 4096 + n) * 1536 + hh * 64 + seg * 8;
      uint4 vq = *(const uint4*)p;
      uint4 vk = *(const uint4*)(p + 512);
      unsigned uq[4] = {vq.x, vq.y, vq.z, vq.w};
      unsigned uk[4] = {vk.x, vk.y, vk.z, vk.w};
      float qf[8], kf[8], sq = 0.f, sk = 0.f;
#pragma unroll
      for (int e = 0; e < 4; e++) {
        float2 f = bfp2f(uq[e]); qf[2 * e] = f.x; qf[2 * e + 1] = f.y; sq += f.x * f.x + f.y * f.y;
        float2 g = bfp2f(uk[e]); kf[2 * e] = g.x; kf[2 * e + 1] = g.y; sk += g.x * g.x + g.y * g.y;
      }
      sq += __shfl_xor(sq, 1); sq += __shfl_xor(sq, 2); sq += __shfl_xor(sq, 4);
      sk += __shfl_xor(sk, 1); sk += __shfl_xor(sk, 2); sk += __shfl_xor(sk, 4);
      float scq = 0.125f * rsqrtf(fmaxf(sq, 1e-12f));
      float sck = rsqrtf(fmaxf(sk, 1e-12f));
      int col = ((c ^ sw) << 3) + tok8;
#pragma unroll
      for (int j = 0; j < 8; j++) {
        int dim = seg * 8 + j;
        qT[dim * 40 + col] = f2bf(qf[j] * scq);
        kT[dim * 40 + col] = f2bf(kf[j] * sck);
      }
    }
    bf16x8 af[4], bfr[4];
#pragma unroll
    for (int mi = 0; mi < 4; mi++) {
      int s3 = (mi * 2 + (rr >> 3)) & 3;
      int off = (mi * 16 + rr) * 40 + ((quad ^ s3) << 3);
      af[mi] = *(const bf16x8*)(qT + off);
      bfr[mi] = *(const bf16x8*)(kT + off);
    }
#pragma unroll
    for (int mi = 0; mi < 4; mi++)
#pragma unroll
      for (int ni = 0; ni < 4; ni++)
        acc[mi][ni] = __builtin_amdgcn_mfma_f32_16x16x32_bf16(af[mi], bfr[ni], acc[mi][ni], 0, 0, 0);
  }

  __syncthreads();  // staging tiles dead; ps takes over first 16KB
  for (int r2 = 0; r2 < 4; r2++) {
    if (w == r2) {
#pragma unroll
      for (int mi = 0; mi < 4; mi++)
#pragma unroll
        for (int ni = 0; ni < 4; ni++)
#pragma unroll
          for (int r = 0; r < 4; r++) {
            int d = mi * 16 + quad * 4 + r, e = ni * 16 + rr;
            if (r2 == 0) ps[d * 64 + e] = acc[mi][ni][r];
            else         ps[d * 64 + e] += acc[mi][ni][r];
          }
    }
    __syncthreads();
  }
  float* outp = logits_p + ((size_t)(b * 8 + hh) * ATTN_CH + chunk) * 4096;
  for (int i = tid; i < 4096; i += 256) outp[i] = ps[i];
}

// ---------- 4) fused chunk-reduce + softmax + M_b = attn @ w_proj -> Mt bf16 ----------
__global__ __launch_bounds__(256) void k_softmax_m(const float* __restrict__ logits_p,
                                                   const float* __restrict__ wproj,
                                                   unsigned short* __restrict__ Mt) {
  int cc = blockIdx.x & 3, rh = blockIdx.x >> 2;
  int hh = blockIdx.y, b = blockIdx.z;
  int t = threadIdx.x;
  __shared__ float ls[32][64];
  __shared__ float red[32][8];
  __shared__ float inv[32];
  const float* lp = logits_p + (size_t)((b * 8 + hh) * ATTN_CH) * 4096 + rh * 2048;
#pragma unroll
  for (int i = 0; i < 8; i++) {
    int id = t + i * 256;               // 0..2047 over [32 rows][64]
    float s = 0.f;
#pragma unroll
    for (int c = 0; c < ATTN_CH; c++) s += lp[c * 4096 + id];
    ls[id >> 6][id & 63] = s;
  }
  __syncthreads();
  int row = t >> 3, part = t & 7;       // 8 threads per row
  float mx = -1e30f;
#pragma unroll
  for (int j = 0; j < 8; j++) mx = fmaxf(mx, ls[row][part * 8 + j]);
  red[row][part] = mx;
  __syncthreads();
  if (part == 0) {
    float m2 = red[row][0];
#pragma unroll
    for (int j = 1; j < 8; j++) m2 = fmaxf(m2, red[row][j]);
    inv[row] = m2;
  }
  __syncthreads();
  float rm = inv[row];
  float s = 0.f;
#pragma unroll
  for (int j = 0; j < 8; j++) {
    float e = __expf(ls[row][part * 8 + j] - rm);
    ls[row][part * 8 + j] = e;
    s += e;
  }
  red[row][part] = s;
  __syncthreads();
  if (part == 0) {
    float s2 = 0.f;
#pragma unroll
    for (int j = 0; j < 8; j++) s2 += red[row][j];
    inv[row] = 1.0f / s2;
  }
  __syncthreads();

  int cout = cc * 128 + (t & 127);
  int half = t >> 7;                    // 0..1 -> 16 rows each
  float wreg[64];
#pragma unroll
  for (int ee = 0; ee < 64; ee++) wreg[ee] = wproj[(size_t)(hh * 64 + ee) * 512 + cout];
  unsigned short ob[16];
#pragma unroll
  for (int d2 = 0; d2 < 16; d2++) {
    int dd = half * 16 + d2;            // local row 0..31
    float a = 0.f;
#pragma unroll
    for (int e4 = 0; e4 < 16; e4++) {
      float4 p4 = *(const float4*)&ls[dd][e4 * 4];
      a += p4.x * wreg[e4 * 4] + p4.y * wreg[e4 * 4 + 1] + p4.z * wreg[e4 * 4 + 2] + p4.w * wreg[e4 * 4 + 3];
    }
    ob[d2] = f2bf(a * inv[dd]);
  }
  uint4* dst = (uint4*)(Mt + ((size_t)(b * 512 + cout)) * 512 + hh * 64 + rh * 32 + half * 16);
  dst[0] = ((const uint4*)ob)[0];
  dst[1] = ((const uint4*)ob)[1];
}

// ---------- 5) out GEMM: per b, V[4096x512] @ M_b^T + b_proj -> fp32 ----------
// Same 256x256 deep-pipelined structure as k_gemm_qkv. 256 blocks: each XCD
// owns one b -> V panel (4MB) + Mt (512KB) L2-resident.
__global__ __launch_bounds__(512, 2) void k_gemm_out(const unsigned short* __restrict__ QKV,
                                                     const unsigned short* __restrict__ MtAll,
                                                     const float* __restrict__ bias,
                                                     float* __restrict__ Out) {
  const int LDA = 1536, LDB = 512, LDC = 512;
  int bid = blockIdx.x;                  // 256 blocks
  int xcd = bid & 7, local = bid >> 3;   // local 0..31
  int gid = xcd * 32 + local;
  int b = gid >> 5;
  int id = gid & 31;
  int m0 = (id >> 1) * 256;
  int n0 = (id & 1) * 256;
  const unsigned short* A = QKV + (size_t)b * NN * 1536 + 1024;  // v slice
  const unsigned short* Bt = MtAll + (size_t)b * 512 * 512;

  int tid = threadIdx.x;
  int lane = tid & 63, w = tid >> 6;
  int wrb = (w >> 2) * 128;
  int wcb = (w & 3) * 64;
  int quad = lane >> 4, rr = lane & 15;
  int r8 = lane >> 3, cg = lane & 7;
  int cgs8 = (cg ^ r8) * 8;
  const int swz = rr & 7;
  int w8 = w * 8;

  __shared__ __align__(16) unsigned short As[2][256 * 64];
  __shared__ __align__(16) unsigned short Bs[2][256 * 64];

  floatx4 acc[8][4];
#pragma unroll
  for (int i = 0; i < 8; i++)
#pragma unroll
    for (int j = 0; j < 4; j++) acc[i][j] = (floatx4){0.f, 0.f, 0.f, 0.f};

  auto stage = [&](int ss, int kt) {
    int k0 = kt << 6;
#pragma unroll
    for (int i = 0; i < 4; i++) {
      int rb = i * 64 + w8;
      async_ld16(&As[ss][rb * 64], A + (size_t)(m0 + rb + r8) * LDA + k0 + cgs8);
      async_ld16(&Bs[ss][rb * 64], Bt + (size_t)(n0 + rb + r8) * LDB + k0 + cgs8);
    }
  };

  auto compute = [&](int ss) {
#pragma unroll
    for (int kk = 0; kk < 2; kk++) {
      int ksl = (((kk << 2) + quad) ^ swz) << 3;
      bf16x8 af[8];
#pragma unroll
      for (int mi = 0; mi < 8; mi++)
        af[mi] = *(const bf16x8*)&As[ss][(wrb + mi * 16 + rr) * 64 + ksl];
      bf16x8 bf[2];
#pragma unroll
      for (int ni = 0; ni < 2; ni++)
        bf[ni] = *(const bf16x8*)&Bs[ss][(wcb + ni * 16 + rr) * 64 + ksl];
      __builtin_amdgcn_s_setprio(1);
#pragma unroll
      for (int mi = 0; mi < 8; mi++)
#pragma unroll
        for (int ni = 0; ni < 2; ni++)
          acc[mi][ni] = __builtin_amdgcn_mfma_f32_16x16x32_bf16(af[mi], bf[ni], acc[mi][ni], 0, 0, 0);
      __builtin_amdgcn_s_setprio(0);
#pragma unroll
      for (int ni = 0; ni < 2; ni++)
        bf[ni] = *(const bf16x8*)&Bs[ss][(wcb + (ni + 2) * 16 + rr) * 64 + ksl];
      __builtin_amdgcn_s_setprio(1);
#pragma unroll
      for (int mi = 0; mi < 8; mi++)
#pragma unroll
        for (int ni = 0; ni < 2; ni++)
          acc[mi][ni + 2] = __builtin_amdgcn_mfma_f32_16x16x32_bf16(af[mi], bf[ni], acc[mi][ni + 2], 0, 0, 0);
      __builtin_amdgcn_s_setprio(0);
    }
  };

  stage(0, 0);
  stage(1, 1);
#pragma unroll 1
  for (int t = 0; t < 8; t++) {
    if (t < 7) asm volatile("s_waitcnt vmcnt(8)" ::: "memory");
    else       asm volatile("s_waitcnt vmcnt(0)" ::: "memory");
    __builtin_amdgcn_s_barrier();
    __builtin_amdgcn_sched_barrier(0);
    compute(t & 1);
    __builtin_amdgcn_sched_barrier(0);
    __builtin_amdgcn_s_barrier();
    if (t < 6) stage(t & 1, t + 2);
  }

#pragma unroll
  for (int ni = 0; ni < 4; ni++) {
    int col = n0 + wcb + ni * 16 + rr;
    float bv = bias[col];
#pragma unroll
    for (int mi = 0; mi < 8; mi++) {
      int rbase = m0 + wrb + mi * 16 + quad * 4;
#pragma unroll
      for (int r = 0; r < 4; r++)
        Out[(size_t)b * NN * LDC + (size_t)(rbase + r) * LDC + col] = acc[mi][ni][r] + bv;
    }
  }
}

extern "C" void kernel_launch(void* const* d_in, const int* in_sizes, int n_in,
                              void* d_out, int out_size, void* d_ws, size_t ws_size,
                              hipStream_t stream) {
  const float* x      = (const float*)d_in[0];
  const float* w_qkv  = (const float*)d_in[1];
  const float* b_qkv  = (const float*)d_in[2];
  const float* w_proj = (const float*)d_in[3];
  const float* b_proj = (const float*)d_in[4];
  float* out = (float*)d_out;

  char* ws = (char*)d_ws;
  size_t off = 0;
  auto alloc = [&](size_t bytes) -> void* {
    void* p = ws + off;
    off += (bytes + 255) & ~(size_t)255;
    return p;
  };
  unsigned short* xb       = (unsigned short*)alloc((size_t)NB * NN * NC * 2);
  unsigned short* wT       = (unsigned short*)alloc((size_t)1536 * 512 * 2);
  unsigned short* qkvb     = (unsigned short*)alloc((size_t)NB * NN * 3 * NC * 2);
  float*          logits_p = (float*)alloc((size_t)NB * NH * ATTN_CH * 4096 * 4);
  unsigned short* Mt       = (unsigned short*)alloc((size_t)NB * 512 * 512 * 2);

  k_prep<<<16576, 256, 0, stream>>>(x, xb, w_qkv, wT);
  k_gemm_qkv<<<768, 512, 0, stream>>>(xb, wT, b_qkv, qkvb);
  k_attn<<<dim3(ATTN_CH, 8, 8), 256, 0, stream>>>(qkvb, logits_p);
  k_softmax_m<<<dim3(8, 8, 8), 256, 0, stream>>>(logits_p, w_proj, Mt);
  k_gemm_out<<<256, 512, 0, stream>>>(qkvb, Mt, b_proj, out);
}

// Round 2
// 260.367 us; speedup vs baseline: 1.1041x; 1.1041x over previous
//
#include <hip/hip_runtime.h>
#include <stdint.h>

// Problem: B=8, N=4096, C=512, H=8, D=64. fp32 in/out, bf16 MFMA internally.
#define NB 8
#define NN 4096
#define NC 512
#define NH 8
#define ATTN_CH 16   // token chunks for k_attn

typedef __bf16 bf16x8 __attribute__((ext_vector_type(8)));
typedef float floatx4 __attribute__((ext_vector_type(4)));

__device__ __forceinline__ unsigned short f2bf(float f) {
  union { float f; unsigned u; } v; v.f = f;
  return (unsigned short)((v.u + 0x7fffu + ((v.u >> 16) & 1u)) >> 16);
}
__device__ __forceinline__ float2 bfp2f(unsigned u) {
  union { unsigned x; float f; } lo, hi;
  lo.x = u << 16; hi.x = u & 0xffff0000u;
  return make_float2(lo.f, hi.f);
}

// async 16B global->LDS (DMA). LDS dest = wave-uniform base + lane*16.
__device__ __forceinline__ void async_ld16(void* lds, const void* g) {
  auto* gp = (const __attribute__((address_space(1))) unsigned int*)(uintptr_t)g;
  auto* lp = (__attribute__((address_space(3))) unsigned int*)(uintptr_t)lds;
  __builtin_amdgcn_global_load_lds(gp, lp, 16, 0, 0);
}

// ---------- 1) fused: x fp32->bf16 convert  +  w_qkv transpose->bf16 ----------
__global__ __launch_bounds__(256) void k_prep(const float* __restrict__ x,
                                              unsigned short* __restrict__ xb,
                                              const float* __restrict__ w,
                                              unsigned short* __restrict__ wt) {
  int bid = blockIdx.x;
  if (bid < 16384) {
    int i = (bid * 256 + threadIdx.x) * 4;
    float4 v = *(const float4*)(x + i);
    ushort4 o;
    o.x = f2bf(v.x); o.y = f2bf(v.y); o.z = f2bf(v.z); o.w = f2bf(v.w);
    *(ushort4*)(xb + i) = o;
    return;
  }
  // transpose 64x64 tile of w [512][1536] -> wt [1536][512]
  __shared__ float tile[64][65];
  int b2 = bid - 16384;                  // 0..191
  int nn0 = (b2 % 24) * 64, kk0 = (b2 / 24) * 64;
  int t = threadIdx.x;
#pragma unroll
  for (int i = 0; i < 16; i++) {
    int id = t + i * 256;
    int r = id >> 6, c = id & 63;
    tile[c][r] = w[(size_t)(kk0 + r) * 1536 + nn0 + c];
  }
  __syncthreads();
#pragma unroll
  for (int i = 0; i < 16; i++) {
    int id = t + i * 256;
    int rn = id >> 6, ck = id & 63;
    wt[(size_t)(nn0 + rn) * 512 + kk0 + ck] = f2bf(tile[rn][ck]);
  }
}

// ---------- 2) qkv GEMM: [32768x512] @ [512x1536] + bias -> bf16 ----------
// 128x128 tile, 4 waves, 2 blocks/CU (cross-block overlap), counted vmcnt:
// A staged 3-deep (HBM stream), B staged 2-deep (L2-resident panel).
// One raw s_barrier + one vmcnt(4) per K-tile; no full drains in main loop.
__global__ __launch_bounds__(256, 2) void k_gemm_qkv(const unsigned short* __restrict__ A,   // [32768][512]
                                                     const unsigned short* __restrict__ Bt,  // [1536][512]
                                                     const float* __restrict__ bias,         // [1536]
                                                     unsigned short* __restrict__ Cq) {      // [32768][1536]
  const int LDA = 512, LDB = 512, LDC = 1536;
  int bid = blockIdx.x;
  int xcd = bid & 7, local = bid >> 3;
  int mloc = local / 12, nt = local - mloc * 12;
  int m0 = (xcd * 32 + mloc) * 128, n0 = nt * 128;

  int tid = threadIdx.x;
  int lane = tid & 63, w = tid >> 6;
  int wm = (w & 1) * 64, wn = (w >> 1) * 64;
  int quad = lane >> 4, rr = lane & 15;
  int r8 = lane >> 3, cg = lane & 7;
  int cgs8 = (cg ^ r8) * 8;
  const int swz = rr & 7;

  __shared__ __align__(16) unsigned short Als[3][128 * 64];
  __shared__ __align__(16) unsigned short Bls[2][128 * 64];

  floatx4 acc[4][4];
#pragma unroll
  for (int i = 0; i < 4; i++)
#pragma unroll
    for (int j = 0; j < 4; j++) acc[i][j] = (floatx4){0.f, 0.f, 0.f, 0.f};

  auto stageA = [&](int ss, int kt) {
    int k0 = kt << 6;
#pragma unroll
    for (int i = 0; i < 4; i++) {
      int rb = i * 32 + w * 8;
      async_ld16(&Als[ss][rb * 64], A + (size_t)(m0 + rb + r8) * LDA + k0 + cgs8);
    }
  };
  auto stageB = [&](int ss, int kt) {
    int k0 = kt << 6;
#pragma unroll
    for (int i = 0; i < 4; i++) {
      int rb = i * 32 + w * 8;
      async_ld16(&Bls[ss][rb * 64], Bt + (size_t)(n0 + rb + r8) * LDB + k0 + cgs8);
    }
  };

  auto computeK = [&](int sa, int sb, int gb) {
    bf16x8 af[4], bfr[4];
#pragma unroll
    for (int mi = 0; mi < 4; mi++)
      af[mi] = *(const bf16x8*)&Als[sa][(wm + mi * 16 + rr) * 64 + (((gb + quad) ^ swz)) * 8];
#pragma unroll
    for (int ni = 0; ni < 4; ni++)
      bfr[ni] = *(const bf16x8*)&Bls[sb][(wn + ni * 16 + rr) * 64 + (((gb + quad) ^ swz)) * 8];
    __builtin_amdgcn_s_setprio(1);
#pragma unroll
    for (int mi = 0; mi < 4; mi++)
#pragma unroll
      for (int ni = 0; ni < 4; ni++)
        acc[mi][ni] = __builtin_amdgcn_mfma_f32_16x16x32_bf16(af[mi], bfr[ni], acc[mi][ni], 0, 0, 0);
    __builtin_amdgcn_s_setprio(0);
  };

  // prologue issue order: B0, A0, A1  (12 loads in flight)
  stageB(0, 0); stageA(0, 0); stageA(1, 1);
  int sa = 0;
#pragma unroll 1
  for (int t = 0; t < 8; t++) {
    // in flight at entry: A(t), B(t), A(t+1)  ->  leave only A(t+1)
    if (t < 7) asm volatile("s_waitcnt vmcnt(4)" ::: "memory");
    else       asm volatile("s_waitcnt vmcnt(0)" ::: "memory");
    asm volatile("s_barrier" ::: "memory");   // all waves' DMAs for tile t resident
    if (t < 7) stageB((t + 1) & 1, t + 1);    // into B(t-1)'s buffer (dead)
    if (t < 6) { int s2 = sa + 2; if (s2 >= 3) s2 -= 3; stageA(s2, t + 2); }  // into A(t-1)'s buffer (dead)
    __builtin_amdgcn_sched_barrier(0);
    computeK(sa, t & 1, 0);
    computeK(sa, t & 1, 4);
    sa = (sa + 1 < 3) ? sa + 1 : 0;
  }

#pragma unroll
  for (int ni = 0; ni < 4; ni++) {
    int col = n0 + wn + ni * 16 + rr;
    float bv = bias[col];
#pragma unroll
    for (int mi = 0; mi < 4; mi++) {
      int rbase = m0 + wm + mi * 16 + quad * 4;
#pragma unroll
      for (int r = 0; r < 4; r++)
        Cq[(size_t)(rbase + r) * LDC + col] = f2bf(acc[mi][ni][r] + bv);
    }
  }
}

// ---------- 3) attn logits via MFMA, fused L2-norm. grid (chunk16, h8, b8) ----------
__global__ __launch_bounds__(256) void k_attn(const unsigned short* __restrict__ QKV,
                                              float* __restrict__ logits_p) {
  int chunk = blockIdx.x, hh = blockIdx.y, b = blockIdx.z;
  int tid = threadIdx.x, w = tid >> 6, l = tid & 63;
  int quad = l >> 4, rr = l & 15;

  __shared__ __align__(16) unsigned char smem[40960];
  unsigned short* qT = (unsigned short*)smem + w * 5120;   // 64*40 halfwords
  unsigned short* kT = qT + 2560;
  float* ps = (float*)smem;                                 // 16KB, reused after barrier

  floatx4 acc[4][4];
#pragma unroll
  for (int i = 0; i < 4; i++)
#pragma unroll
    for (int j = 0; j < 4; j++) acc[i][j] = (floatx4){0.f, 0.f, 0.f, 0.f};

  int tok8 = l >> 3;
  int seg = l & 7;
  int sw = seg & 3;

  for (int s = 0; s < 2; s++) {
    int nbase = chunk * 256 + w * 64 + s * 32;
#pragma unroll
    for (int c = 0; c < 4; c++) {
      int n = nbase + c * 8 + tok8;
      const unsigned short* p = QKV + (size_t)(b * 4096 + n) * 1536 + hh * 64 + seg * 8;
      uint4 vq = *(const uint4*)p;
      uint4 vk = *(const uint4*)(p + 512);
      unsigned uq[4] = {vq.x, vq.y, vq.z, vq.w};
      unsigned uk[4] = {vk.x, vk.y, vk.z, vk.w};
      float qf[8], kf[8], sq = 0.f, sk = 0.f;
#pragma unroll
      for (int e = 0; e < 4; e++) {
        float2 f = bfp2f(uq[e]); qf[2 * e] = f.x; qf[2 * e + 1] = f.y; sq += f.x * f.x + f.y * f.y;
        float2 g = bfp2f(uk[e]); kf[2 * e] = g.x; kf[2 * e + 1] = g.y; sk += g.x * g.x + g.y * g.y;
      }
      sq += __shfl_xor(sq, 1); sq += __shfl_xor(sq, 2); sq += __shfl_xor(sq, 4);
      sk += __shfl_xor(sk, 1); sk += __shfl_xor(sk, 2); sk += __shfl_xor(sk, 4);
      float scq = 0.125f * rsqrtf(fmaxf(sq, 1e-12f));
      float sck = rsqrtf(fmaxf(sk, 1e-12f));
      int col = ((c ^ sw) << 3) + tok8;
#pragma unroll
      for (int j = 0; j < 8; j++) {
        int dim = seg * 8 + j;
        qT[dim * 40 + col] = f2bf(qf[j] * scq);
        kT[dim * 40 + col] = f2bf(kf[j] * sck);
      }
    }
    bf16x8 af[4], bfr[4];
#pragma unroll
    for (int mi = 0; mi < 4; mi++) {
      int s3 = (mi * 2 + (rr >> 3)) & 3;
      int off = (mi * 16 + rr) * 40 + ((quad ^ s3) << 3);
      af[mi] = *(const bf16x8*)(qT + off);
      bfr[mi] = *(const bf16x8*)(kT + off);
    }
#pragma unroll
    for (int mi = 0; mi < 4; mi++)
#pragma unroll
      for (int ni = 0; ni < 4; ni++)
        acc[mi][ni] = __builtin_amdgcn_mfma_f32_16x16x32_bf16(af[mi], bfr[ni], acc[mi][ni], 0, 0, 0);
  }

  __syncthreads();  // staging tiles dead; ps takes over first 16KB
  for (int r2 = 0; r2 < 4; r2++) {
    if (w == r2) {
#pragma unroll
      for (int mi = 0; mi < 4; mi++)
#pragma unroll
        for (int ni = 0; ni < 4; ni++)
#pragma unroll
          for (int r = 0; r < 4; r++) {
            int d = mi * 16 + quad * 4 + r, e = ni * 16 + rr;
            if (r2 == 0) ps[d * 64 + e] = acc[mi][ni][r];
            else         ps[d * 64 + e] += acc[mi][ni][r];
          }
    }
    __syncthreads();
  }
  float* outp = logits_p + ((size_t)(b * 8 + hh) * ATTN_CH + chunk) * 4096;
  for (int i = tid; i < 4096; i += 256) outp[i] = ps[i];
}

// ---------- 4) fused chunk-reduce + softmax + M_b = attn @ w_proj -> Mt bf16 ----------
__global__ __launch_bounds__(256) void k_softmax_m(const float* __restrict__ logits_p,
                                                   const float* __restrict__ wproj,
                                                   unsigned short* __restrict__ Mt) {
  int cc = blockIdx.x & 3, rh = blockIdx.x >> 2;
  int hh = blockIdx.y, b = blockIdx.z;
  int t = threadIdx.x;
  __shared__ float ls[32][64];
  __shared__ float red[32][8];
  __shared__ float inv[32];
  const float* lp = logits_p + (size_t)((b * 8 + hh) * ATTN_CH) * 4096 + rh * 2048;
#pragma unroll
  for (int i = 0; i < 8; i++) {
    int id = t + i * 256;               // 0..2047 over [32 rows][64]
    float s = 0.f;
#pragma unroll
    for (int c = 0; c < ATTN_CH; c++) s += lp[c * 4096 + id];
    ls[id >> 6][id & 63] = s;
  }
  __syncthreads();
  int row = t >> 3, part = t & 7;       // 8 threads per row
  float mx = -1e30f;
#pragma unroll
  for (int j = 0; j < 8; j++) mx = fmaxf(mx, ls[row][part * 8 + j]);
  red[row][part] = mx;
  __syncthreads();
  if (part == 0) {
    float m2 = red[row][0];
#pragma unroll
    for (int j = 1; j < 8; j++) m2 = fmaxf(m2, red[row][j]);
    inv[row] = m2;
  }
  __syncthreads();
  float rm = inv[row];
  float s = 0.f;
#pragma unroll
  for (int j = 0; j < 8; j++) {
    float e = __expf(ls[row][part * 8 + j] - rm);
    ls[row][part * 8 + j] = e;
    s += e;
  }
  red[row][part] = s;
  __syncthreads();
  if (part == 0) {
    float s2 = 0.f;
#pragma unroll
    for (int j = 0; j < 8; j++) s2 += red[row][j];
    inv[row] = 1.0f / s2;
  }
  __syncthreads();

  int cout = cc * 128 + (t & 127);
  int half = t >> 7;                    // 0..1 -> 16 rows each
  float wreg[64];
#pragma unroll
  for (int ee = 0; ee < 64; ee++) wreg[ee] = wproj[(size_t)(hh * 64 + ee) * 512 + cout];
  unsigned short ob[16];
#pragma unroll
  for (int d2 = 0; d2 < 16; d2++) {
    int dd = half * 16 + d2;            // local row 0..31
    float a = 0.f;
#pragma unroll
    for (int e4 = 0; e4 < 16; e4++) {
      float4 p4 = *(const float4*)&ls[dd][e4 * 4];
      a += p4.x * wreg[e4 * 4] + p4.y * wreg[e4 * 4 + 1] + p4.z * wreg[e4 * 4 + 2] + p4.w * wreg[e4 * 4 + 3];
    }
    ob[d2] = f2bf(a * inv[dd]);
  }
  uint4* dst = (uint4*)(Mt + ((size_t)(b * 512 + cout)) * 512 + hh * 64 + rh * 32 + half * 16);
  dst[0] = ((const uint4*)ob)[0];
  dst[1] = ((const uint4*)ob)[1];
}

// ---------- 5) out GEMM: per b, V[4096x512] @ M_b^T + b_proj -> fp32 ----------
// Same counted-vmcnt 128x128 structure as k_gemm_qkv.
__global__ __launch_bounds__(256, 2) void k_gemm_out(const unsigned short* __restrict__ QKV,
                                                     const unsigned short* __restrict__ MtAll,
                                                     const float* __restrict__ bias,
                                                     float* __restrict__ Out) {
  const int LDA = 1536, LDB = 512, LDC = 512;
  int bid = blockIdx.x;
  int xcd = bid & 7, local = bid >> 3;
  int mloc = local >> 2, nt = local & 3;
  int g = xcd * 32 + mloc;
  int b = g >> 5;
  int m0 = (g & 31) * 128;
  int n0 = nt * 128;
  const unsigned short* A = QKV + (size_t)b * NN * 1536 + 1024;  // v slice
  const unsigned short* Bt = MtAll + (size_t)b * 512 * 512;
  int tid = threadIdx.x;
  int lane = tid & 63, w = tid >> 6;
  int wm = (w & 1) * 64, wn = (w >> 1) * 64;
  int quad = lane >> 4, rr = lane & 15;
  int r8 = lane >> 3, cg = lane & 7;
  int cgs8 = (cg ^ r8) * 8;
  const int swz = rr & 7;

  __shared__ __align__(16) unsigned short Als[3][128 * 64];
  __shared__ __align__(16) unsigned short Bls[2][128 * 64];

  floatx4 acc[4][4];
#pragma unroll
  for (int i = 0; i < 4; i++)
#pragma unroll
    for (int j = 0; j < 4; j++) acc[i][j] = (floatx4){0.f, 0.f, 0.f, 0.f};

  auto stageA = [&](int ss, int kt) {
    int k0 = kt << 6;
#pragma unroll
    for (int i = 0; i < 4; i++) {
      int rb = i * 32 + w * 8;
      async_ld16(&Als[ss][rb * 64], A + (size_t)(m0 + rb + r8) * LDA + k0 + cgs8);
    }
  };
  auto stageB = [&](int ss, int kt) {
    int k0 = kt << 6;
#pragma unroll
    for (int i = 0; i < 4; i++) {
      int rb = i * 32 + w * 8;
      async_ld16(&Bls[ss][rb * 64], Bt + (size_t)(n0 + rb + r8) * LDB + k0 + cgs8);
    }
  };

  auto computeK = [&](int sa, int sb, int gb) {
    bf16x8 af[4], bfr[4];
#pragma unroll
    for (int mi = 0; mi < 4; mi++)
      af[mi] = *(const bf16x8*)&Als[sa][(wm + mi * 16 + rr) * 64 + (((gb + quad) ^ swz)) * 8];
#pragma unroll
    for (int ni = 0; ni < 4; ni++)
      bfr[ni] = *(const bf16x8*)&Bls[sb][(wn + ni * 16 + rr) * 64 + (((gb + quad) ^ swz)) * 8];
    __builtin_amdgcn_s_setprio(1);
#pragma unroll
    for (int mi = 0; mi < 4; mi++)
#pragma unroll
      for (int ni = 0; ni < 4; ni++)
        acc[mi][ni] = __builtin_amdgcn_mfma_f32_16x16x32_bf16(af[mi], bfr[ni], acc[mi][ni], 0, 0, 0);
    __builtin_amdgcn_s_setprio(0);
  };

  stageB(0, 0); stageA(0, 0); stageA(1, 1);
  int sa = 0;
#pragma unroll 1
  for (int t = 0; t < 8; t++) {
    if (t < 7) asm volatile("s_waitcnt vmcnt(4)" ::: "memory");
    else       asm volatile("s_waitcnt vmcnt(0)" ::: "memory");
    asm volatile("s_barrier" ::: "memory");
    if (t < 7) stageB((t + 1) & 1, t + 1);
    if (t < 6) { int s2 = sa + 2; if (s2 >= 3) s2 -= 3; stageA(s2, t + 2); }
    __builtin_amdgcn_sched_barrier(0);
    computeK(sa, t & 1, 0);
    computeK(sa, t & 1, 4);
    sa = (sa + 1 < 3) ? sa + 1 : 0;
  }

#pragma unroll
  for (int ni = 0; ni < 4; ni++) {
    int col = n0 + wn + ni * 16 + rr;
    float bv = bias[col];
#pragma unroll
    for (int mi = 0; mi < 4; mi++) {
      int rbase = m0 + wm + mi * 16 + quad * 4;
#pragma unroll
      for (int r = 0; r < 4; r++)
        Out[(size_t)b * NN * LDC + (size_t)(rbase + r) * LDC + col] = acc[mi][ni][r] + bv;
    }
  }
}

extern "C" void kernel_launch(void* const* d_in, const int* in_sizes, int n_in,
                              void* d_out, int out_size, void* d_ws, size_t ws_size,
                              hipStream_t stream) {
  const float* x      = (const float*)d_in[0];
  const float* w_qkv  = (const float*)d_in[1];
  const float* b_qkv  = (const float*)d_in[2];
  const float* w_proj = (const float*)d_in[3];
  const float* b_proj = (const float*)d_in[4];
  float* out = (float*)d_out;

  char* ws = (char*)d_ws;
  size_t off = 0;
  auto alloc = [&](size_t bytes) -> void* {
    void* p = ws + off;
    off += (bytes + 255) & ~(size_t)255;
    return p;
  };
  unsigned short* xb       = (unsigned short*)alloc((size_t)NB * NN * NC * 2);
  unsigned short* wT       = (unsigned short*)alloc((size_t)1536 * 512 * 2);
  unsigned short* qkvb     = (unsigned short*)alloc((size_t)NB * NN * 3 * NC * 2);
  float*          logits_p = (float*)alloc((size_t)NB * NH * ATTN_CH * 4096 * 4);
  unsigned short* Mt       = (unsigned short*)alloc((size_t)NB * 512 * 512 * 2);

  k_prep<<<16576, 256, 0, stream>>>(x, xb, w_qkv, wT);
  k_gemm_qkv<<<3072, 256, 0, stream>>>(xb, wT, b_qkv, qkvb);
  k_attn<<<dim3(ATTN_CH, 8, 8), 256, 0, stream>>>(qkvb, logits_p);
  k_softmax_m<<<dim3(8, 8, 8), 256, 0, stream>>>(logits_p, w_proj, Mt);
  k_gemm_out<<<1024, 256, 0, stream>>>(qkvb, Mt, b_proj, out);
}